// Round 10
// baseline (170.211 us; speedup 1.0000x reference)
//
#include <hip/hip_runtime.h>

#define NN 16
#define NO 32
#define XCOLS 133

typedef _Float16 h8v __attribute__((ext_vector_type(8)));
typedef float f4v __attribute__((ext_vector_type(4)));
typedef unsigned ui4 __attribute__((ext_vector_type(4)));
typedef float f4u __attribute__((ext_vector_type(4), aligned(4)));

static __device__ __forceinline__ f4v MFMA(h8v a, h8v b, f4v c) {
    return __builtin_amdgcn_mfma_f32_16x16x32_f16(a, b, c, 0, 0, 0);
}
static __device__ __forceinline__ unsigned pkbits(float a, float b) {
    return __builtin_bit_cast(unsigned, __builtin_amdgcn_cvt_pkrtz(a, b));
}

// ---------------------------------------------------------------------------
// prep (parallel, verified): pack weights into MFMA B-fragment arrays.
// B[k][col]: col = 16*nt + (lane&15), k = 32*kc + 8*(lane>>4) + j; zero-padded.
// ---------------------------------------------------------------------------
__global__ void prep_frags(
    const float* __restrict__ pnW1, const float* __restrict__ pnW2,
    const float* __restrict__ rnW1, const float* __restrict__ rnW2,
    const float* __restrict__ poW1, const float* __restrict__ poW2,
    const float* __restrict__ roW1, const float* __restrict__ roW2,
    const float* __restrict__ psW1, const float* __restrict__ psW2,
    const float* __restrict__ psW3, unsigned* __restrict__ ws)
{
    const float* Ws[11] = {pnW1,pnW2,rnW1,rnW2,poW1,poW2,roW1,roW2,psW1,psW2,psW3};
    const int Kr[11]   = {4,64,16,64,2,64,16,64,18,64,64};
    const int Nr[11]   = {64,16,64,8,64,16,64,8,64,64,2};
    const int nkc[11]  = {1,2,1,2,1,2,1,2,1,2,2};
    const int nnt[11]  = {4,1,4,1,4,1,4,1,4,4,1};
    const int base[11] = {0,1024,1536,2560,3072,4096,4608,5632,6144,7168,9216};

    const int gid = blockIdx.x * 256 + threadIdx.x;   // 0..9727
    int start = 0;
    #pragma unroll
    for (int a2 = 0; a2 < 11; ++a2) {
        const int n = nkc[a2] * nnt[a2] * 256;
        if (gid >= start && gid < start + n) {
            const int i = gid - start;
            const float* Wm = Ws[a2];
            const int K = Kr[a2], N = Nr[a2], nt_n = nnt[a2];
            const int d = i & 3, lane = (i >> 2) & 63, t = i >> 8;
            const int nt = t % nt_n, kc = t / nt_n;
            const int k = kc * 32 + 8 * (lane >> 4) + 2 * d;
            const int col = nt * 16 + (lane & 15);
            const float v0 = (k     < K && col < N) ? Wm[(k    ) * N + col] : 0.f;
            const float v1 = (k + 1 < K && col < N) ? Wm[(k + 1) * N + col] : 0.f;
            ws[base[a2] + i] = pkbits(v0, v1);
        }
        start += n;
    }
}

// ---------------------------------------------------------------------------
// main: 256 threads = 4 INDEPENDENT waves (no barriers), wave = 16 elements.
// ILP structure: L1-neighbor and L1-obstacle fused in one loop (12 MFMAs +
// 2 relu-acc chains per iter); dense N-chain and O-chain interleaved per
// stage (separate PN/PO scratch) until they join at F.
// Per-wave LDS (f16): POOL@0[1024], TBUF@1024[1024], PN@2048[512],
// PO@2560[512], HB@3072[512], barf@3584(32 f32). Total 3648 f16 = 7296 B.
// ---------------------------------------------------------------------------
__global__ __launch_bounds__(256, 4) void barrier_net_kernel(
    const float* __restrict__ x, const float* __restrict__ noise,
    const float* __restrict__ pnb1, const float* __restrict__ pnb2,
    const float* __restrict__ rnb1, const float* __restrict__ rnb2,
    const float* __restrict__ pob1, const float* __restrict__ pob2,
    const float* __restrict__ rob1, const float* __restrict__ rob2,
    const float* __restrict__ psb1, const float* __restrict__ psb2,
    const float* __restrict__ psb3,
    const unsigned* __restrict__ wsu, float* __restrict__ out)
{
    __shared__ _Float16 smem[4][3648];

    const int tid = threadIdx.x;
    const int l = tid & 63;
    const int w = tid >> 6;
    const int r = l & 15;
    const int g = l >> 4;
    const int eb = blockIdx.x * 64 + w * 16;

    _Float16* W = &smem[w][0];
    float* barf = (float*)(W + 3584);
    const h8v* FB = (const h8v*)wsu;

    {   // zero PN+PO+HB (2048..3584 = 768 dwords, 12/lane)
        unsigned* z = (unsigned*)(W + 2048);
        #pragma unroll
        for (int i = 0; i < 12; ++i) z[l + 64 * i] = 0u;
    }

    const size_t xrow = (size_t)(eb + r) * XCOLS;
    const int sw8 = (r & 7) << 3;
    const int sw4 = (r & 3) << 3;

    // ============ L1 fused: neighbor pt t + obstacle pts 2t,2t+1 ==============
    {
        const h8v BN0 = FB[0*64 + l], BN1 = FB[1*64 + l];
        const h8v BN2 = FB[2*64 + l], BN3 = FB[3*64 + l];
        const h8v BO0 = FB[768 + 0*64 + l], BO1 = FB[768 + 1*64 + l];
        const h8v BO2 = FB[768 + 2*64 + l], BO3 = FB[768 + 3*64 + l];
        const f4v cN0 = {pnb1[r], pnb1[r], pnb1[r], pnb1[r]};
        const f4v cN1 = {pnb1[16+r], pnb1[16+r], pnb1[16+r], pnb1[16+r]};
        const f4v cN2 = {pnb1[32+r], pnb1[32+r], pnb1[32+r], pnb1[32+r]};
        const f4v cN3 = {pnb1[48+r], pnb1[48+r], pnb1[48+r], pnb1[48+r]};
        const f4v cO0 = {pob1[r], pob1[r], pob1[r], pob1[r]};
        const f4v cO1 = {pob1[16+r], pob1[16+r], pob1[16+r], pob1[16+r]};
        const f4v cO2 = {pob1[32+r], pob1[32+r], pob1[32+r], pob1[32+r]};
        const f4v cO3 = {pob1[48+r], pob1[48+r], pob1[48+r], pob1[48+r]};
        f4v sN0 = {0,0,0,0}, sN1 = {0,0,0,0}, sN2 = {0,0,0,0}, sN3 = {0,0,0,0};
        f4v sO0 = {0,0,0,0}, sO1 = {0,0,0,0}, sO2 = {0,0,0,0}, sO3 = {0,0,0,0};
        const float* pxn = x + xrow + 5;
        const float* pxo = x + xrow + 69;
        #pragma unroll 2
        for (int t = 0; t < 16; ++t) {
            const f4u vN = *(const f4u*)(pxn + 4*t);
            const f4u vO = *(const f4u*)(pxo + 4*t);
            ui4 auN = {pkbits(vN[0], vN[1]), pkbits(vN[2], vN[3]), 0u, 0u};
            ui4 auO0 = {pkbits(vO[0], vO[1]), 0u, 0u, 0u};
            ui4 auO1 = {pkbits(vO[2], vO[3]), 0u, 0u, 0u};
            const h8v aN  = __builtin_bit_cast(h8v, auN);
            const h8v aO0 = __builtin_bit_cast(h8v, auO0);
            const h8v aO1 = __builtin_bit_cast(h8v, auO1);
            const f4v dN0 = MFMA(aN, BN0, cN0);
            const f4v dN1 = MFMA(aN, BN1, cN1);
            const f4v dN2 = MFMA(aN, BN2, cN2);
            const f4v dN3 = MFMA(aN, BN3, cN3);
            const f4v dO0 = MFMA(aO0, BO0, cO0); const f4v eO0 = MFMA(aO1, BO0, cO0);
            const f4v dO1 = MFMA(aO0, BO1, cO1); const f4v eO1 = MFMA(aO1, BO1, cO1);
            const f4v dO2 = MFMA(aO0, BO2, cO2); const f4v eO2 = MFMA(aO1, BO2, cO2);
            const f4v dO3 = MFMA(aO0, BO3, cO3); const f4v eO3 = MFMA(aO1, BO3, cO3);
            #pragma unroll
            for (int q = 0; q < 4; ++q) {
                sN0[q] += fmaxf(dN0[q], 0.f); sN1[q] += fmaxf(dN1[q], 0.f);
                sN2[q] += fmaxf(dN2[q], 0.f); sN3[q] += fmaxf(dN3[q], 0.f);
                sO0[q] += fmaxf(dO0[q], 0.f) + fmaxf(eO0[q], 0.f);
                sO1[q] += fmaxf(dO1[q], 0.f) + fmaxf(eO1[q], 0.f);
                sO2[q] += fmaxf(dO2[q], 0.f) + fmaxf(eO2[q], 0.f);
                sO3[q] += fmaxf(dO3[q], 0.f) + fmaxf(eO3[q], 0.f);
            }
        }
        #pragma unroll
        for (int q = 0; q < 4; ++q) {
            const int e = 4 * g + q;
            const int m = (e & 7) << 3;
            W[e*64 + (( 0 + r) ^ m)] = (_Float16)sN0[q];
            W[e*64 + ((16 + r) ^ m)] = (_Float16)sN1[q];
            W[e*64 + ((32 + r) ^ m)] = (_Float16)sN2[q];
            W[e*64 + ((48 + r) ^ m)] = (_Float16)sN3[q];
            W[1024 + e*64 + (( 0 + r) ^ m)] = (_Float16)sO0[q];
            W[1024 + e*64 + ((16 + r) ^ m)] = (_Float16)sO1[q];
            W[1024 + e*64 + ((32 + r) ^ m)] = (_Float16)sO2[q];
            W[1024 + e*64 + ((48 + r) ^ m)] = (_Float16)sO3[q];
        }
    }

    // ============ barrier pass (dedup'd across g) ============
    {
        float bq0 = 0.f, bq1 = 0.f;
        const float* pxn = x + xrow + 5;
        #pragma unroll
        for (int jj = 0; jj < 4; ++jj) {
            const int j = 4 * g + jj;
            const float v0 = pxn[4*j], v1 = pxn[4*j + 1];
            const float nrm = sqrtf(v0*v0 + v1*v1);
            const float cc = 0.01f * __builtin_amdgcn_rcpf(nrm * (nrm - 0.3f));
            bq0 -= cc * v0; bq1 -= cc * v1;
        }
        const float* pxo = x + xrow + 69;
        #pragma unroll
        for (int jj = 0; jj < 8; ++jj) {
            const int j = 8 * g + jj;
            const float v0 = pxo[2*j], v1 = pxo[2*j + 1];
            const float nrm = sqrtf(v0*v0 + v1*v1);
            const float cc = 0.01f * __builtin_amdgcn_rcpf(nrm * (nrm - 0.5f));
            bq0 -= cc * v0; bq1 -= cc * v1;
        }
        bq0 += __shfl_xor(bq0, 16); bq0 += __shfl_xor(bq0, 32);
        bq1 += __shfl_xor(bq1, 16); bq1 += __shfl_xor(bq1, 32);
        if (g == 0) { barf[2*r] = bq0; barf[2*r + 1] = bq1; }
    }

    // ============ C ∥ C': pn/po = s @ W2 + count*b2 -> PN / PO ============
    {
        h8v aN0 = *(const h8v*)&W[r*64 + (( 0 + 8*g) ^ sw8)];
        h8v aN1 = *(const h8v*)&W[r*64 + ((32 + 8*g) ^ sw8)];
        h8v aO0 = *(const h8v*)&W[1024 + r*64 + (( 0 + 8*g) ^ sw8)];
        h8v aO1 = *(const h8v*)&W[1024 + r*64 + ((32 + 8*g) ^ sw8)];
        h8v bN0 = FB[256 + 0*64 + l], bN1 = FB[256 + 1*64 + l];
        h8v bO0 = FB[1024 + 0*64 + l], bO1 = FB[1024 + 1*64 + l];
        const float bbN = 16.f * pnb2[r];
        const float bbO = 32.f * pob2[r];
        f4v cN = {bbN, bbN, bbN, bbN};
        f4v cO = {bbO, bbO, bbO, bbO};
        f4v dN = MFMA(aN1, bN1, MFMA(aN0, bN0, cN));
        f4v dO = MFMA(aO1, bO1, MFMA(aO0, bO0, cO));
        #pragma unroll
        for (int q = 0; q < 4; ++q) {
            const int row = 4 * g + q;
            const int sm = (row & 3) << 3;
            W[2048 + row*32 + (r ^ sm)] = (_Float16)dN[q];
            W[2560 + row*32 + (r ^ sm)] = (_Float16)dO[q];
        }
    }
    // ============ D1 ∥ D1': t = relu(pn@rnW1+rnb1) -> POOL / TBUF ============
    {
        h8v aN = *(const h8v*)&W[2048 + r*32 + ((8*g) ^ sw4)];
        h8v aO = *(const h8v*)&W[2560 + r*32 + ((8*g) ^ sw4)];
        #pragma unroll
        for (int nt = 0; nt < 4; ++nt) {
            h8v bN = FB[384 + nt*64 + l];
            h8v bO = FB[1152 + nt*64 + l];
            const float bbN = rnb1[16*nt + r];
            const float bbO = rob1[16*nt + r];
            f4v cN = {bbN, bbN, bbN, bbN};
            f4v cO = {bbO, bbO, bbO, bbO};
            f4v dN = MFMA(aN, bN, cN);
            f4v dO = MFMA(aO, bO, cO);
            #pragma unroll
            for (int q = 0; q < 4; ++q) {
                const int row = 4 * g + q;
                const int sm = (row & 7) << 3;
                W[row*64 + ((16*nt + r) ^ sm)] = (_Float16)fmaxf(dN[q], 0.f);
                W[1024 + row*64 + ((16*nt + r) ^ sm)] = (_Float16)fmaxf(dO[q], 0.f);
            }
        }
    }
    // ============ D2 ∥ D2': rn/ro -> HB cols 0..7 / 8..15 ============
    {
        h8v aN0 = *(const h8v*)&W[r*64 + (( 0 + 8*g) ^ sw8)];
        h8v aN1 = *(const h8v*)&W[r*64 + ((32 + 8*g) ^ sw8)];
        h8v aO0 = *(const h8v*)&W[1024 + r*64 + (( 0 + 8*g) ^ sw8)];
        h8v aO1 = *(const h8v*)&W[1024 + r*64 + ((32 + 8*g) ^ sw8)];
        h8v bN0 = FB[640 + 0*64 + l], bN1 = FB[640 + 1*64 + l];
        h8v bO0 = FB[1408 + 0*64 + l], bO1 = FB[1408 + 1*64 + l];
        const float bbN = (r < 8) ? rnb2[r & 7] : 0.f;
        const float bbO = (r < 8) ? rob2[r & 7] : 0.f;
        f4v cN = {bbN, bbN, bbN, bbN};
        f4v cO = {bbO, bbO, bbO, bbO};
        f4v dN = MFMA(aN1, bN1, MFMA(aN0, bN0, cN));
        f4v dO = MFMA(aO1, bO1, MFMA(aO0, bO0, cO));
        if (r < 8) {
            #pragma unroll
            for (int q = 0; q < 4; ++q) {
                const int row = 4 * g + q;
                const int sm = (row & 3) << 3;
                W[3072 + row*32 + (r ^ sm)] = (_Float16)dN[q];
                W[3072 + row*32 + ((8 + r) ^ sm)] = (_Float16)dO[q];
            }
        }
    }
    // ============ goal cols 16,17 into HB ============
    if (g == 0) {
        const float gx = x[xrow + 1];
        const float gy = x[xrow + 2];
        W[3072 + r*32 + (16 ^ sw4)] = (_Float16)gx;
        W[3072 + r*32 + (17 ^ sw4)] = (_Float16)gy;
    }
    // ============ F: ha = relu(h @ psW1 + psb1) -> TBUF ============
    {
        h8v a = *(const h8v*)&W[3072 + r*32 + ((8*g) ^ sw4)];
        #pragma unroll
        for (int nt = 0; nt < 4; ++nt) {
            h8v b = FB[1536 + nt*64 + l];
            const float bb = psb1[16*nt + r];
            f4v c = {bb, bb, bb, bb};
            f4v d = MFMA(a, b, c);
            #pragma unroll
            for (int q = 0; q < 4; ++q) {
                const int row = 4 * g + q;
                W[1024 + row*64 + ((16*nt + r) ^ ((row & 7) << 3))] = (_Float16)fmaxf(d[q], 0.f);
            }
        }
    }
    // ============ G1: t2 = relu(ha @ psW2 + psb2) -> POOL ============
    {
        h8v a0 = *(const h8v*)&W[1024 + r*64 + (( 0 + 8*g) ^ sw8)];
        h8v a1 = *(const h8v*)&W[1024 + r*64 + ((32 + 8*g) ^ sw8)];
        #pragma unroll
        for (int nt = 0; nt < 4; ++nt) {
            h8v b0 = FB[1792 + (0*4 + nt)*64 + l];
            h8v b1 = FB[1792 + (1*4 + nt)*64 + l];
            const float bb = psb2[16*nt + r];
            f4v c = {bb, bb, bb, bb};
            f4v d = MFMA(a1, b1, MFMA(a0, b0, c));
            #pragma unroll
            for (int q = 0; q < 4; ++q) {
                const int row = 4 * g + q;
                W[row*64 + ((16*nt + r) ^ ((row & 7) << 3))] = (_Float16)fmaxf(d[q], 0.f);
            }
        }
    }
    // ============ G2 + finale ============
    f4v dOut;
    {
        h8v a0 = *(const h8v*)&W[r*64 + (( 0 + 8*g) ^ sw8)];
        h8v a1 = *(const h8v*)&W[r*64 + ((32 + 8*g) ^ sw8)];
        h8v b0 = FB[2304 + 0*64 + l];
        h8v b1 = FB[2304 + 1*64 + l];
        const float bb = (r < 2) ? psb3[r & 1] : 0.f;
        f4v c = {bb, bb, bb, bb};
        dOut = MFMA(a1, b1, MFMA(a0, b0, c));
    }
    if (r < 2) {
        #pragma unroll
        for (int q = 0; q < 4; ++q) {
            const int e = 4 * g + q;
            const float o = dOut[q];
            const float bar = barf[e*2 + r];
            const float nz = noise[2 * (size_t)(eb + e) + r];
            const float av = tanhf(2.f * tanhf(o) + bar + nz);
            out[2 * (size_t)(eb + e) + r] = 2.f * av;
        }
    }
}

extern "C" void kernel_launch(void* const* d_in, const int* in_sizes, int n_in,
                              void* d_out, int out_size, void* d_ws, size_t ws_size,
                              hipStream_t stream) {
    const float* x    = (const float*)d_in[0];
    const float* nz   = (const float*)d_in[1];
    const float* pnW1 = (const float*)d_in[2];
    const float* pnb1 = (const float*)d_in[3];
    const float* pnW2 = (const float*)d_in[4];
    const float* pnb2 = (const float*)d_in[5];
    const float* rnW1 = (const float*)d_in[6];
    const float* rnb1 = (const float*)d_in[7];
    const float* rnW2 = (const float*)d_in[8];
    const float* rnb2 = (const float*)d_in[9];
    const float* poW1 = (const float*)d_in[10];
    const float* pob1 = (const float*)d_in[11];
    const float* poW2 = (const float*)d_in[12];
    const float* pob2 = (const float*)d_in[13];
    const float* roW1 = (const float*)d_in[14];
    const float* rob1 = (const float*)d_in[15];
    const float* roW2 = (const float*)d_in[16];
    const float* rob2 = (const float*)d_in[17];
    const float* psW1 = (const float*)d_in[18];
    const float* psb1 = (const float*)d_in[19];
    const float* psW2 = (const float*)d_in[20];
    const float* psb2 = (const float*)d_in[21];
    const float* psW3 = (const float*)d_in[22];
    const float* psb3 = (const float*)d_in[23];

    unsigned* ws = (unsigned*)d_ws;
    hipLaunchKernelGGL(prep_frags, dim3(38), dim3(256), 0, stream,
        pnW1, pnW2, rnW1, rnW2, poW1, poW2, roW1, roW2, psW1, psW2, psW3, ws);

    const int b = in_sizes[0] / XCOLS;
    hipLaunchKernelGGL(barrier_net_kernel, dim3(b / 64), dim3(256), 0, stream,
        x, nz, pnb1, pnb2, rnb1, rnb2, pob1, pob2, rob1, rob2,
        psb1, psb2, psb3, ws, (float*)d_out);
}

// Round 11
// 44.756 us; speedup vs baseline: 3.8031x; 3.8031x over previous
//
#include <hip/hip_runtime.h>

#define NN 16
#define NO 32
#define XCOLS 133

typedef _Float16 h8v __attribute__((ext_vector_type(8)));
typedef _Float16 h2 __attribute__((ext_vector_type(2)));
typedef float f4v __attribute__((ext_vector_type(4)));
typedef unsigned ui4 __attribute__((ext_vector_type(4)));
typedef float f2u __attribute__((ext_vector_type(2), aligned(4)));

static __device__ __forceinline__ f4v MFMA(h8v a, h8v b, f4v c) {
    return __builtin_amdgcn_mfma_f32_16x16x32_f16(a, b, c, 0, 0, 0);
}
static __device__ __forceinline__ unsigned pkbits(float a, float b) {
    return __builtin_bit_cast(unsigned, __builtin_amdgcn_cvt_pkrtz(a, b));
}
static __device__ __forceinline__ h2 u2h(unsigned v) { return __builtin_bit_cast(h2, v); }

// ---------------------------------------------------------------------------
// prep (parallel, verified): pack weights into MFMA B-fragment arrays.
// B[k][col]: col = 16*nt + (lane&15), k = 32*kc + 8*(lane>>4) + j; zero-padded.
// ---------------------------------------------------------------------------
__global__ void prep_frags(
    const float* __restrict__ pnW1, const float* __restrict__ pnW2,
    const float* __restrict__ rnW1, const float* __restrict__ rnW2,
    const float* __restrict__ poW1, const float* __restrict__ poW2,
    const float* __restrict__ roW1, const float* __restrict__ roW2,
    const float* __restrict__ psW1, const float* __restrict__ psW2,
    const float* __restrict__ psW3, unsigned* __restrict__ ws)
{
    const float* Ws[11] = {pnW1,pnW2,rnW1,rnW2,poW1,poW2,roW1,roW2,psW1,psW2,psW3};
    const int Kr[11]   = {4,64,16,64,2,64,16,64,18,64,64};
    const int Nr[11]   = {64,16,64,8,64,16,64,8,64,64,2};
    const int nkc[11]  = {1,2,1,2,1,2,1,2,1,2,2};
    const int nnt[11]  = {4,1,4,1,4,1,4,1,4,4,1};
    const int base[11] = {0,1024,1536,2560,3072,4096,4608,5632,6144,7168,9216};

    const int gid = blockIdx.x * 256 + threadIdx.x;   // 0..9727
    int start = 0;
    #pragma unroll
    for (int a2 = 0; a2 < 11; ++a2) {
        const int n = nkc[a2] * nnt[a2] * 256;
        if (gid >= start && gid < start + n) {
            const int i = gid - start;
            const float* Wm = Ws[a2];
            const int K = Kr[a2], N = Nr[a2], nt_n = nnt[a2];
            const int d = i & 3, lane = (i >> 2) & 63, t = i >> 8;
            const int nt = t % nt_n, kc = t / nt_n;
            const int k = kc * 32 + 8 * (lane >> 4) + 2 * d;
            const int col = nt * 16 + (lane & 15);
            const float v0 = (k     < K && col < N) ? Wm[(k    ) * N + col] : 0.f;
            const float v1 = (k + 1 < K && col < N) ? Wm[(k + 1) * N + col] : 0.f;
            ws[base[a2] + i] = pkbits(v0, v1);
        }
        start += n;
    }
}

// ---------------------------------------------------------------------------
// main: 64-thread (1-wave) blocks, 16 elements each (R9 structure).
// NEW: x is burst-staged into LDS up-front — 16 coalesced 512B row-loads into
// statically-indexed registers (full MLP), packed f16 pairs -> XS[16][66]
// (stride 66 dwords: 16 rows hit 16 distinct banks; 4-way broadcast free).
// L1 / barrier / goal all read XS; no global access inside dependent loops.
// LDS: XS 4224B + W 6272B = 10496B.
// ---------------------------------------------------------------------------
__global__ __launch_bounds__(64, 4) void barrier_net_kernel(
    const float* __restrict__ x, const float* __restrict__ noise,
    const float* __restrict__ pnb1, const float* __restrict__ pnb2,
    const float* __restrict__ rnb1, const float* __restrict__ rnb2,
    const float* __restrict__ pob1, const float* __restrict__ pob2,
    const float* __restrict__ rob1, const float* __restrict__ rob2,
    const float* __restrict__ psb1, const float* __restrict__ psb2,
    const float* __restrict__ psb3,
    const unsigned* __restrict__ wsu, float* __restrict__ out)
{
    __shared__ unsigned XS[16 * 66];   // staged f16 pairs: row rr, pair p at XS[rr*66+p]
    __shared__ _Float16 W[3136];       // POOL@0, TBUF@1024, PN@2048, HB@2560, barf@3072

    const int l = threadIdx.x;
    const int r = l & 15;
    const int g = l >> 4;
    const int eb = blockIdx.x * 16;

    float* barf = (float*)(W + 3072);
    const h8v* FB = (const h8v*)wsu;

    // ---- burst-stage x: 16 rows x 128 floats (cols 5..132) + goal (cols 1,2)
    {
        const float* base = x + (size_t)eb * XCOLS;
        f2u raw[16];
        #pragma unroll
        for (int it = 0; it < 16; ++it)
            raw[it] = *(const f2u*)(base + (size_t)it * XCOLS + 5 + 2 * l);
        f2u graw = {0.f, 0.f};
        if (l < 16) graw = *(const f2u*)(base + (size_t)l * XCOLS + 1);
        #pragma unroll
        for (int it = 0; it < 16; ++it)
            XS[it * 66 + l] = pkbits(raw[it][0], raw[it][1]);
        if (l < 16) XS[l * 66 + 64] = pkbits(graw[0], graw[1]);
    }

    {   // zero PN+HB (2048..3072 f16 = 512 dwords, 8/lane)
        unsigned* z = (unsigned*)(W + 2048);
        #pragma unroll
        for (int i = 0; i < 8; ++i) z[l + 64 * i] = 0u;
    }

    const int rowb = r * 66;
    const int sw8 = (r & 7) << 3;
    const int sw4 = (r & 3) << 3;

    // ================= barrier pass (dedup'd across g, from XS) ===============
    {
        float bq0 = 0.f, bq1 = 0.f;
        #pragma unroll
        for (int jj = 0; jj < 4; ++jj) {
            const h2 v = u2h(XS[rowb + 2 * (4 * g + jj)]);     // neighbor j pos
            const float v0 = (float)v[0], v1 = (float)v[1];
            const float nrm = sqrtf(v0*v0 + v1*v1);
            const float cc = 0.01f * __builtin_amdgcn_rcpf(nrm * (nrm - 0.3f));
            bq0 -= cc * v0; bq1 -= cc * v1;
        }
        #pragma unroll
        for (int jj = 0; jj < 8; ++jj) {
            const h2 v = u2h(XS[rowb + 32 + 8 * g + jj]);      // obstacle j pos
            const float v0 = (float)v[0], v1 = (float)v[1];
            const float nrm = sqrtf(v0*v0 + v1*v1);
            const float cc = 0.01f * __builtin_amdgcn_rcpf(nrm * (nrm - 0.5f));
            bq0 -= cc * v0; bq1 -= cc * v1;
        }
        bq0 += __shfl_xor(bq0, 16); bq0 += __shfl_xor(bq0, 32);
        bq1 += __shfl_xor(bq1, 16); bq1 += __shfl_xor(bq1, 32);
        if (g == 0) { barf[2*r] = bq0; barf[2*r + 1] = bq1; }
    }

    // ================= L1 neighbor: point-loop from XS ========================
    {
        const h8v B0 = FB[0*64 + l], B1 = FB[1*64 + l];
        const h8v B2 = FB[2*64 + l], B3 = FB[3*64 + l];
        const f4v c0 = {pnb1[r], pnb1[r], pnb1[r], pnb1[r]};
        const f4v c1 = {pnb1[16+r], pnb1[16+r], pnb1[16+r], pnb1[16+r]};
        const f4v c2 = {pnb1[32+r], pnb1[32+r], pnb1[32+r], pnb1[32+r]};
        const f4v c3 = {pnb1[48+r], pnb1[48+r], pnb1[48+r], pnb1[48+r]};
        f4v s0 = {0,0,0,0}, s1 = {0,0,0,0}, s2 = {0,0,0,0}, s3 = {0,0,0,0};
        #pragma unroll 4
        for (int j = 0; j < NN; ++j) {
            const uint2 np = *(const uint2*)&XS[rowb + 2 * j];  // 4 feats (8B-aligned)
            ui4 au = {np.x, np.y, 0u, 0u};
            const h8v a = __builtin_bit_cast(h8v, au);
            const f4v d0 = MFMA(a, B0, c0);
            const f4v d1 = MFMA(a, B1, c1);
            const f4v d2 = MFMA(a, B2, c2);
            const f4v d3 = MFMA(a, B3, c3);
            #pragma unroll
            for (int q = 0; q < 4; ++q) {
                s0[q] += fmaxf(d0[q], 0.f); s1[q] += fmaxf(d1[q], 0.f);
                s2[q] += fmaxf(d2[q], 0.f); s3[q] += fmaxf(d3[q], 0.f);
            }
        }
        #pragma unroll
        for (int q = 0; q < 4; ++q) {
            const int e = 4 * g + q;
            const int m = (e & 7) << 3;
            W[e*64 + (( 0 + r) ^ m)] = (_Float16)s0[q];
            W[e*64 + ((16 + r) ^ m)] = (_Float16)s1[q];
            W[e*64 + ((32 + r) ^ m)] = (_Float16)s2[q];
            W[e*64 + ((48 + r) ^ m)] = (_Float16)s3[q];
        }
    }

    // ================= L1 obstacle: point-loop from XS, 2 pts/iter ============
    {
        const h8v B0 = FB[768 + 0*64 + l], B1 = FB[768 + 1*64 + l];
        const h8v B2 = FB[768 + 2*64 + l], B3 = FB[768 + 3*64 + l];
        const f4v c0 = {pob1[r], pob1[r], pob1[r], pob1[r]};
        const f4v c1 = {pob1[16+r], pob1[16+r], pob1[16+r], pob1[16+r]};
        const f4v c2 = {pob1[32+r], pob1[32+r], pob1[32+r], pob1[32+r]};
        const f4v c3 = {pob1[48+r], pob1[48+r], pob1[48+r], pob1[48+r]};
        f4v s0 = {0,0,0,0}, s1 = {0,0,0,0}, s2 = {0,0,0,0}, s3 = {0,0,0,0};
        #pragma unroll 2
        for (int t = 0; t < 16; ++t) {
            const uint2 op = *(const uint2*)&XS[rowb + 32 + 2 * t];  // 2 points
            ui4 au0 = {op.x, 0u, 0u, 0u};
            ui4 au1 = {op.y, 0u, 0u, 0u};
            const h8v a0 = __builtin_bit_cast(h8v, au0);
            const h8v a1 = __builtin_bit_cast(h8v, au1);
            const f4v d0 = MFMA(a0, B0, c0); const f4v e0 = MFMA(a1, B0, c0);
            const f4v d1 = MFMA(a0, B1, c1); const f4v e1 = MFMA(a1, B1, c1);
            const f4v d2 = MFMA(a0, B2, c2); const f4v e2 = MFMA(a1, B2, c2);
            const f4v d3 = MFMA(a0, B3, c3); const f4v e3 = MFMA(a1, B3, c3);
            #pragma unroll
            for (int q = 0; q < 4; ++q) {
                s0[q] += fmaxf(d0[q], 0.f) + fmaxf(e0[q], 0.f);
                s1[q] += fmaxf(d1[q], 0.f) + fmaxf(e1[q], 0.f);
                s2[q] += fmaxf(d2[q], 0.f) + fmaxf(e2[q], 0.f);
                s3[q] += fmaxf(d3[q], 0.f) + fmaxf(e3[q], 0.f);
            }
        }
        #pragma unroll
        for (int q = 0; q < 4; ++q) {
            const int e = 4 * g + q;
            const int m = (e & 7) << 3;
            W[1024 + e*64 + (( 0 + r) ^ m)] = (_Float16)s0[q];
            W[1024 + e*64 + ((16 + r) ^ m)] = (_Float16)s1[q];
            W[1024 + e*64 + ((32 + r) ^ m)] = (_Float16)s2[q];
            W[1024 + e*64 + ((48 + r) ^ m)] = (_Float16)s3[q];
        }
    }

    // ================= C: pn = sn @ pnW2 + 16*pnb2 -> PN ======================
    {
        h8v a0 = *(const h8v*)&W[r*64 + (( 0 + 8*g) ^ sw8)];
        h8v a1 = *(const h8v*)&W[r*64 + ((32 + 8*g) ^ sw8)];
        h8v b0 = FB[256 + 0*64 + l];
        h8v b1 = FB[256 + 1*64 + l];
        const float bb = 16.f * pnb2[r];
        f4v c = {bb, bb, bb, bb};
        f4v d = MFMA(a1, b1, MFMA(a0, b0, c));
        #pragma unroll
        for (int q = 0; q < 4; ++q) {
            const int row = 4 * g + q;
            W[2048 + row*32 + (r ^ ((row&3)<<3))] = (_Float16)d[q];
        }
    }
    // ================= D1: t = relu(pn @ rnW1 + rnb1) -> POOL =================
    {
        h8v a = *(const h8v*)&W[2048 + r*32 + ((8*g) ^ sw4)];
        #pragma unroll
        for (int nt = 0; nt < 4; ++nt) {
            h8v b = FB[384 + nt*64 + l];
            const float bb = rnb1[16*nt + r];
            f4v c = {bb, bb, bb, bb};
            f4v d = MFMA(a, b, c);
            #pragma unroll
            for (int q = 0; q < 4; ++q) {
                const int row = 4 * g + q;
                W[row*64 + ((16*nt + r) ^ ((row&7)<<3))] = (_Float16)fmaxf(d[q], 0.f);
            }
        }
    }
    // ================= D2: rn = t @ rnW2 + rnb2 -> HB cols 0..7 ===============
    {
        h8v a0 = *(const h8v*)&W[r*64 + (( 0 + 8*g) ^ sw8)];
        h8v a1 = *(const h8v*)&W[r*64 + ((32 + 8*g) ^ sw8)];
        h8v b0 = FB[640 + 0*64 + l];
        h8v b1 = FB[640 + 1*64 + l];
        const float bb = (r < 8) ? rnb2[r & 7] : 0.f;
        f4v c = {bb, bb, bb, bb};
        f4v d = MFMA(a1, b1, MFMA(a0, b0, c));
        if (r < 8) {
            #pragma unroll
            for (int q = 0; q < 4; ++q) {
                const int row = 4 * g + q;
                W[2560 + row*32 + (r ^ ((row&3)<<3))] = (_Float16)d[q];
            }
        }
    }
    // ================= C': po = so @ poW2 + 32*pob2 -> PN =====================
    {
        h8v a0 = *(const h8v*)&W[1024 + r*64 + (( 0 + 8*g) ^ sw8)];
        h8v a1 = *(const h8v*)&W[1024 + r*64 + ((32 + 8*g) ^ sw8)];
        h8v b0 = FB[1024 + 0*64 + l];
        h8v b1 = FB[1024 + 1*64 + l];
        const float bb = 32.f * pob2[r];
        f4v c = {bb, bb, bb, bb};
        f4v d = MFMA(a1, b1, MFMA(a0, b0, c));
        #pragma unroll
        for (int q = 0; q < 4; ++q) {
            const int row = 4 * g + q;
            W[2048 + row*32 + (r ^ ((row&3)<<3))] = (_Float16)d[q];
        }
    }
    // ================= D1': t2 = relu(po @ roW1 + rob1) -> POOL ===============
    {
        h8v a = *(const h8v*)&W[2048 + r*32 + ((8*g) ^ sw4)];
        #pragma unroll
        for (int nt = 0; nt < 4; ++nt) {
            h8v b = FB[1152 + nt*64 + l];
            const float bb = rob1[16*nt + r];
            f4v c = {bb, bb, bb, bb};
            f4v d = MFMA(a, b, c);
            #pragma unroll
            for (int q = 0; q < 4; ++q) {
                const int row = 4 * g + q;
                W[row*64 + ((16*nt + r) ^ ((row&7)<<3))] = (_Float16)fmaxf(d[q], 0.f);
            }
        }
    }
    // ================= D2': ro = t2 @ roW2 + rob2 -> HB cols 8..15 ============
    {
        h8v a0 = *(const h8v*)&W[r*64 + (( 0 + 8*g) ^ sw8)];
        h8v a1 = *(const h8v*)&W[r*64 + ((32 + 8*g) ^ sw8)];
        h8v b0 = FB[1408 + 0*64 + l];
        h8v b1 = FB[1408 + 1*64 + l];
        const float bb = (r < 8) ? rob2[r & 7] : 0.f;
        f4v c = {bb, bb, bb, bb};
        f4v d = MFMA(a1, b1, MFMA(a0, b0, c));
        if (r < 8) {
            #pragma unroll
            for (int q = 0; q < 4; ++q) {
                const int row = 4 * g + q;
                W[2560 + row*32 + ((8 + r) ^ ((row&3)<<3))] = (_Float16)d[q];
            }
        }
    }
    // ================= goal cols 16,17 into HB (from XS) ======================
    if (g == 0) {
        const h2 gv = u2h(XS[rowb + 64]);
        W[2560 + r*32 + (16 ^ sw4)] = gv[0];
        W[2560 + r*32 + (17 ^ sw4)] = gv[1];
    }
    // ================= F: ha = relu(h @ psW1 + psb1) -> TBUF ==================
    {
        h8v a = *(const h8v*)&W[2560 + r*32 + ((8*g) ^ sw4)];
        #pragma unroll
        for (int nt = 0; nt < 4; ++nt) {
            h8v b = FB[1536 + nt*64 + l];
            const float bb = psb1[16*nt + r];
            f4v c = {bb, bb, bb, bb};
            f4v d = MFMA(a, b, c);
            #pragma unroll
            for (int q = 0; q < 4; ++q) {
                const int row = 4 * g + q;
                W[1024 + row*64 + ((16*nt + r) ^ ((row&7)<<3))] = (_Float16)fmaxf(d[q], 0.f);
            }
        }
    }
    // ================= G1: t2 = relu(ha @ psW2 + psb2) -> POOL ================
    {
        h8v a0 = *(const h8v*)&W[1024 + r*64 + (( 0 + 8*g) ^ sw8)];
        h8v a1 = *(const h8v*)&W[1024 + r*64 + ((32 + 8*g) ^ sw8)];
        #pragma unroll
        for (int nt = 0; nt < 4; ++nt) {
            h8v b0 = FB[1792 + (0*4 + nt)*64 + l];
            h8v b1 = FB[1792 + (1*4 + nt)*64 + l];
            const float bb = psb2[16*nt + r];
            f4v c = {bb, bb, bb, bb};
            f4v d = MFMA(a1, b1, MFMA(a0, b0, c));
            #pragma unroll
            for (int q = 0; q < 4; ++q) {
                const int row = 4 * g + q;
                W[row*64 + ((16*nt + r) ^ ((row&7)<<3))] = (_Float16)fmaxf(d[q], 0.f);
            }
        }
    }
    // ================= G2 + finale ============================================
    f4v dOut;
    {
        h8v a0 = *(const h8v*)&W[r*64 + (( 0 + 8*g) ^ sw8)];
        h8v a1 = *(const h8v*)&W[r*64 + ((32 + 8*g) ^ sw8)];
        h8v b0 = FB[2304 + 0*64 + l];
        h8v b1 = FB[2304 + 1*64 + l];
        const float bb = (r < 2) ? psb3[r & 1] : 0.f;
        f4v c = {bb, bb, bb, bb};
        dOut = MFMA(a1, b1, MFMA(a0, b0, c));
    }
    if (r < 2) {
        #pragma unroll
        for (int q = 0; q < 4; ++q) {
            const int e = 4 * g + q;
            const float o = dOut[q];
            const float bar = barf[e*2 + r];
            const float nz = noise[2 * (size_t)(eb + e) + r];
            const float av = tanhf(2.f * tanhf(o) + bar + nz);
            out[2 * (size_t)(eb + e) + r] = 2.f * av;
        }
    }
}

extern "C" void kernel_launch(void* const* d_in, const int* in_sizes, int n_in,
                              void* d_out, int out_size, void* d_ws, size_t ws_size,
                              hipStream_t stream) {
    const float* x    = (const float*)d_in[0];
    const float* nz   = (const float*)d_in[1];
    const float* pnW1 = (const float*)d_in[2];
    const float* pnb1 = (const float*)d_in[3];
    const float* pnW2 = (const float*)d_in[4];
    const float* pnb2 = (const float*)d_in[5];
    const float* rnW1 = (const float*)d_in[6];
    const float* rnb1 = (const float*)d_in[7];
    const float* rnW2 = (const float*)d_in[8];
    const float* rnb2 = (const float*)d_in[9];
    const float* poW1 = (const float*)d_in[10];
    const float* pob1 = (const float*)d_in[11];
    const float* poW2 = (const float*)d_in[12];
    const float* pob2 = (const float*)d_in[13];
    const float* roW1 = (const float*)d_in[14];
    const float* rob1 = (const float*)d_in[15];
    const float* roW2 = (const float*)d_in[16];
    const float* rob2 = (const float*)d_in[17];
    const float* psW1 = (const float*)d_in[18];
    const float* psb1 = (const float*)d_in[19];
    const float* psW2 = (const float*)d_in[20];
    const float* psb2 = (const float*)d_in[21];
    const float* psW3 = (const float*)d_in[22];
    const float* psb3 = (const float*)d_in[23];

    unsigned* ws = (unsigned*)d_ws;
    hipLaunchKernelGGL(prep_frags, dim3(38), dim3(256), 0, stream,
        pnW1, pnW2, rnW1, rnW2, poW1, poW2, roW1, roW2, psW1, psW2, psW3, ws);

    const int b = in_sizes[0] / XCOLS;
    hipLaunchKernelGGL(barrier_net_kernel, dim3(b / 16), dim3(64), 0, stream,
        x, nz, pnb1, pnb2, rnb1, rnb2, pob1, pob2, rob1, rob2,
        psb1, psb2, psb3, ws, (float*)d_out);
}